// Round 2
// baseline (865.130 us; speedup 1.0000x reference)
//
#include <hip/hip_runtime.h>

#define TPB 256
#define NT 7   // N-tiles per wave: 4 waves * 7 = 28 tiles = 448 cols (400 real)

typedef __attribute__((ext_vector_type(8))) short bf16x8;
typedef __attribute__((ext_vector_type(4))) float f32x4;

// round-to-nearest-even fp32 -> bf16 (as raw short)
__device__ __forceinline__ short f2bf(float f) {
    union { float f; unsigned u; } v; v.f = f;
    unsigned r = (v.u + 0x7FFFu + ((v.u >> 16) & 1u)) >> 16;
    return (short)r;
}

__device__ __forceinline__ float frcp(float x) {
#if __has_builtin(__builtin_amdgcn_rcpf)
    return __builtin_amdgcn_rcpf(x);
#else
    return 1.0f / x;
#endif
}

__device__ __forceinline__ float fast_sig(float x) {
    return frcp(1.0f + __expf(-x));
}
__device__ __forceinline__ float fast_tanh(float x) {
    return 1.0f - 2.0f * frcp(1.0f + __expf(2.0f * x));
}

// ---------------------------------------------------------------------------
// Kernel 1: fused  z_t = x_t @ Wi + h_{t-1} @ Wh + bh  -> gates -> c,h
// hs (bf16) to workspace. grid 256 blocks (8 batch rows each), 4 waves.
// ---------------------------------------------------------------------------
__global__ __launch_bounds__(TPB, 1) void lstm_fused(
    const float* __restrict__ x,   // [2048,250,128]
    const float* __restrict__ Wi,  // [128,400]
    const float* __restrict__ Wh,  // [100,400]
    const float* __restrict__ bh,  // [400]
    short* __restrict__ hs)        // [2048,250,100] bf16 workspace
{
    const int tid  = threadIdx.x;
    const int lane = tid & 63;
    const int wave = tid >> 6;
    const int m16  = lane & 15;   // A row / B col within 16-tile
    const int kg   = lane >> 4;   // k-group 0..3
    const int b0   = blockIdx.x * 8;

    __shared__ short xA[16 * 136];        // x_t bf16 A-layout [row][k], rows 8..15 garbage (discarded)
    __shared__ short hA[2][16 * 136];     // h bf16 A-layout, double buffered; k>=100 stays 0
    __shared__ float zld[2][8 * 448];     // z  [r][c], double buffered

    // zero hA (both buffers): h_{-1}=0 and k-pad zeros forever
    for (int i = tid; i < 2 * 16 * 136; i += TPB) ((short*)hA)[i] = 0;

    // ---- preload Wi/Wh B-fragments into registers (shared k-map with A: k = s*32+kg*8+j) ----
    bf16x8 bWi[NT][4], bWh[NT][4];
    float  bhv[NT];
    #pragma unroll
    for (int tI = 0; tI < NT; ++tI) {
        const int c   = (wave * NT + tI) * 16 + m16;
        const bool ok = (c < 400);
        bhv[tI] = ok ? bh[c] : 0.0f;
        #pragma unroll
        for (int s = 0; s < 4; ++s) {
            bf16x8 vi, vh;
            #pragma unroll
            for (int j = 0; j < 8; ++j) {
                const int k = s * 32 + kg * 8 + j;
                vi[j] = f2bf(ok ? Wi[k * 400 + c] : 0.0f);              // k < 128 always
                vh[j] = f2bf((ok && k < 100) ? Wh[k * 400 + c] : 0.0f); // zero-pad K 100..127
            }
            bWi[tI][s] = vi;
            bWh[tI][s] = vh;
        }
    }

    // ---- gate-slot precompute: thread handles (r,hc) pairs flat = s*256+tid < 800 ----
    float cst[4] = {0.f, 0.f, 0.f, 0.f};
    int  zofs[4][4];
    int  hOff[4];
    long hsOff[4];
    bool act[4];
    #pragma unroll
    for (int s = 0; s < 4; ++s) {
        const int flat = s * TPB + tid;
        act[s] = (flat < 800);
        const int fl = act[s] ? flat : 0;
        const int hc = fl % 100;
        const int r  = fl / 100;
        zofs[s][0] = r * 448 + hc;          // i
        zofs[s][1] = r * 448 + hc + 100;    // f
        zofs[s][2] = r * 448 + hc + 200;    // g
        zofs[s][3] = r * 448 + hc + 300;    // o
        hOff[s]  = r * 136 + hc;
        hsOff[s] = ((long)(b0 + r) * 250) * 100 + hc;
    }

    // ---- x prefetch: one float4 per thread covers 8 rows x 128 k ----
    const int  xrow  = tid >> 5;         // 0..7
    const int  xk    = (tid & 31) * 4;   // 0..124
    const long xbase = ((long)(b0 + xrow) * 250) * 128 + xk;
    float4 xp = *(const float4*)&x[xbase];   // t = 0

    const int aoff = m16 * 136 + kg * 8;

    __syncthreads();   // hA zeros visible

    #pragma unroll 1
    for (int t = 0; t < 250; ++t) {
        // P1: stage x_t into xA
        short4 s4;
        s4.x = f2bf(xp.x); s4.y = f2bf(xp.y); s4.z = f2bf(xp.z); s4.w = f2bf(xp.w);
        *(short4*)&xA[xrow * 136 + xk] = s4;
        __syncthreads();   // B1: xA ready, previous gate-phase hA writes ready

        // prefetch x_{t+1}
        const int tn = (t < 249) ? t + 1 : 249;
        xp = *(const float4*)&x[xbase + (long)tn * 128];

        const int pr = (t + 1) & 1;   // hA read buffer (h_{t-1})
        const int pw = t & 1;         // hA write buffer (h_t) and zld buffer

        // P2: MFMA  z = bh + x@Wi + h@Wh
        f32x4 acc[NT];
        #pragma unroll
        for (int tI = 0; tI < NT; ++tI) {
            f32x4 a = {bhv[tI], bhv[tI], bhv[tI], bhv[tI]};
            acc[tI] = a;
        }
        #pragma unroll
        for (int s = 0; s < 4; ++s) {
            const bf16x8 aX = *(const bf16x8*)&xA[aoff + s * 32];
            #pragma unroll
            for (int tI = 0; tI < NT; ++tI)
                acc[tI] = __builtin_amdgcn_mfma_f32_16x16x32_bf16(aX, bWi[tI][s], acc[tI], 0, 0, 0);
        }
        #pragma unroll
        for (int s = 0; s < 4; ++s) {
            const bf16x8 aH = *(const bf16x8*)&hA[pr][aoff + s * 32];
            #pragma unroll
            for (int tI = 0; tI < NT; ++tI)
                acc[tI] = __builtin_amdgcn_mfma_f32_16x16x32_bf16(aH, bWh[tI][s], acc[tI], 0, 0, 0);
        }

        // write z rows 0..7 (C layout: row = kg*4+j, col = tile*16+m16)
        if (kg < 2) {
            #pragma unroll
            for (int tI = 0; tI < NT; ++tI) {
                const int c = (wave * NT + tI) * 16 + m16;
                if (c < 400) {
                    #pragma unroll
                    for (int j = 0; j < 4; ++j)
                        zld[pw][(kg * 4 + j) * 448 + c] = acc[tI][j];
                }
            }
        }
        __syncthreads();   // B2: z ready

        // P3: gates, state update, h writeback (bf16 to LDS and to hs ws)
        #pragma unroll
        for (int s = 0; s < 4; ++s) {
            if (act[s]) {
                const float zi = zld[pw][zofs[s][0]];
                const float zf = zld[pw][zofs[s][1]];
                const float zg = zld[pw][zofs[s][2]];
                const float zo = zld[pw][zofs[s][3]];
                const float ig = fast_sig(zi);
                const float fg = fast_sig(zf);
                const float gg = fast_tanh(zg);
                const float og = fast_sig(zo);
                const float cs = fg * cst[s] + ig * gg;
                cst[s] = cs;
                const float h = og * fast_tanh(cs);
                const short hb = f2bf(h);
                hA[pw][hOff[s]] = hb;
                hs[hsOff[s] + (long)t * 100] = hb;   // same bf16 value the recurrence sees
            }
        }
        // next iteration's B1 separates these hA writes from the next MFMA reads
    }
}

// ---------------------------------------------------------------------------
// Kernel 2: out = relu(hs @ Wd + bd), fp32 output
// grid 8000 blocks (64 rows each), 256 threads
// ---------------------------------------------------------------------------
__global__ __launch_bounds__(TPB) void out_gemm(
    const short* __restrict__ hs,   // [512000,100] bf16
    const float* __restrict__ Wd,   // [100,100]
    const float* __restrict__ bd,   // [100]
    float* __restrict__ out)        // [512000,100] fp32
{
    const int tid  = threadIdx.x;
    const int lane = tid & 63;
    const int wave = tid >> 6;
    const int m16  = lane & 15;
    const int kg   = lane >> 4;
    const long m0  = (long)blockIdx.x * 64;

    __shared__ short hsA[64 * 136];    // A bf16 [row][k], k>=100 zero
    __shared__ short WdT[112 * 136];   // B bf16 transposed [n][k], pads zero

    for (int i = tid; i < 64 * 136; i += TPB)  hsA[i] = 0;
    for (int i = tid; i < 112 * 136; i += TPB) WdT[i] = 0;
    __syncthreads();

    // stage hs tile: 64 rows x 100 bf16 = 1600 short4 units, coalesced 8B loads
    #pragma unroll
    for (int i = 0; i < 7; ++i) {
        const int u = i * TPB + tid;
        if (u < 1600) {
            const int r = u / 25, k4 = u % 25;
            *(short4*)&hsA[r * 136 + k4 * 4] =
                *(const short4*)&hs[m0 * 100 + (long)r * 100 + k4 * 4];
        }
    }
    // stage Wd transposed (10000 floats)
    for (int i = 0; i < 40; ++i) {
        const int idx = i * TPB + tid;
        if (idx < 10000) {
            const int k = idx / 100, n = idx % 100;
            WdT[n * 136 + k] = f2bf(Wd[idx]);
        }
    }
    __syncthreads();

    const int aoff = (wave * 16 + m16) * 136 + kg * 8;
    f32x4 acc[NT];
    #pragma unroll
    for (int tI = 0; tI < NT; ++tI) {
        const int n = tI * 16 + m16;
        const float b = (n < 100) ? bd[n] : 0.0f;
        f32x4 a = {b, b, b, b};
        acc[tI] = a;
    }
    #pragma unroll
    for (int s = 0; s < 4; ++s) {
        const bf16x8 aF = *(const bf16x8*)&hsA[aoff + s * 32];
        #pragma unroll
        for (int tI = 0; tI < NT; ++tI) {
            const bf16x8 bF = *(const bf16x8*)&WdT[(tI * 16 + m16) * 136 + s * 32 + kg * 8];
            acc[tI] = __builtin_amdgcn_mfma_f32_16x16x32_bf16(aF, bF, acc[tI], 0, 0, 0);
        }
    }
    // epilogue: relu + fp32 store (C layout: row = kg*4+j within wave's 16-row group)
    #pragma unroll
    for (int tI = 0; tI < NT; ++tI) {
        const int n = tI * 16 + m16;
        if (n < 100) {
            #pragma unroll
            for (int j = 0; j < 4; ++j) {
                const long row = m0 + wave * 16 + kg * 4 + j;
                float v = acc[tI][j];
                v = v > 0.0f ? v : 0.0f;
                out[row * 100 + n] = v;
            }
        }
    }
}

extern "C" void kernel_launch(void* const* d_in, const int* in_sizes, int n_in,
                              void* d_out, int out_size, void* d_ws, size_t ws_size,
                              hipStream_t stream) {
    (void)in_sizes; (void)n_in; (void)out_size; (void)ws_size;
    const float* x  = (const float*)d_in[0];
    const float* Wi = (const float*)d_in[1];
    const float* Wh = (const float*)d_in[2];
    const float* bh = (const float*)d_in[3];
    const float* Wd = (const float*)d_in[4];
    const float* bd = (const float*)d_in[5];
    short* hsws = (short*)d_ws;           // 512000*100*2 = 102.4 MB bf16
    float* out  = (float*)d_out;          // fp32 output

    lstm_fused<<<256, TPB, 0, stream>>>(x, Wi, Wh, bh, hsws);
    out_gemm<<<8000, TPB, 0, stream>>>(hsws, Wd, bd, out);
}

// Round 3
// 652.838 us; speedup vs baseline: 1.3252x; 1.3252x over previous
//
#include <hip/hip_runtime.h>

#define TPB 512   // 8 waves: wave w owns 16-col group w (H padded 100->128)

typedef __attribute__((ext_vector_type(8))) short bf16x8;
typedef __attribute__((ext_vector_type(4))) float f32x4;

// round-to-nearest-even fp32 -> bf16 (as raw short)
__device__ __forceinline__ short f2bf(float f) {
    union { float f; unsigned u; } v; v.f = f;
    unsigned r = (v.u + 0x7FFFu + ((v.u >> 16) & 1u)) >> 16;
    return (short)r;
}

__device__ __forceinline__ float frcp(float x) {
#if __has_builtin(__builtin_amdgcn_rcpf)
    return __builtin_amdgcn_rcpf(x);
#else
    return 1.0f / x;
#endif
}

__device__ __forceinline__ float fast_sig(float x) {
    return frcp(1.0f + __expf(-x));
}
__device__ __forceinline__ float fast_tanh(float x) {
    return 1.0f - 2.0f * frcp(1.0f + __expf(2.0f * x));
}

// ---------------------------------------------------------------------------
// Fully fused: z_t = x_t@Wi + h_{t-1}@Wh + bh -> gates (in registers) -> c,h
//              out_{t-1} = relu(h_{t-1} @ Wd + bd)  (reuses the aH fragments)
// grid 256 blocks x 8 batch rows, 512 threads (8 waves), 1 barrier per step.
// ---------------------------------------------------------------------------
__global__ __launch_bounds__(TPB, 2) void lstm_fused_all(
    const float* __restrict__ x,   // [2048,250,128]
    const float* __restrict__ Wi,  // [128,400]
    const float* __restrict__ Wh,  // [100,400]
    const float* __restrict__ bh,  // [400]
    const float* __restrict__ Wd,  // [100,100]
    const float* __restrict__ bd,  // [100]
    float* __restrict__ out)       // [2048,250,100]
{
    const int tid  = threadIdx.x;
    const int lane = tid & 63;
    const int wave = tid >> 6;    // 0..7, also the col group AND the staged x row
    const int m16  = lane & 15;
    const int kg   = lane >> 4;   // k-group 0..3
    const int b0   = blockIdx.x * 8;

    __shared__ short xA[2][16 * 136];  // x_t bf16 A-layout [row][k], double buffered
    __shared__ short hA[2][16 * 136];  // h   bf16 A-layout, double buffered; pads stay 0

    for (int i = tid; i < 2 * 16 * 136; i += TPB) ((short*)xA)[i] = 0;
    for (int i = tid; i < 2 * 16 * 136; i += TPB) ((short*)hA)[i] = 0;

    const int  cg    = wave * 16 + m16;   // col within H-padded 128
    const bool valid = (cg < 100);

    // ---- preload fragments: Wi/Wh for all 4 gates of col group `wave`, Wd for out ----
    bf16x8 bWi[4][4], bWh[4][4], bWd[4];
    float  bhv[4];
    #pragma unroll
    for (int G = 0; G < 4; ++G) {
        const int c = G * 100 + cg;
        bhv[G] = valid ? bh[c] : 0.0f;
        #pragma unroll
        for (int s = 0; s < 4; ++s) {
            bf16x8 vi, vh;
            #pragma unroll
            for (int j = 0; j < 8; ++j) {
                const int k = s * 32 + kg * 8 + j;
                vi[j] = f2bf(valid ? Wi[k * 400 + c] : 0.0f);               // K=128 exact
                vh[j] = f2bf((valid && k < 100) ? Wh[k * 400 + c] : 0.0f);  // K pad 100->128
            }
            bWi[G][s] = vi;
            bWh[G][s] = vh;
        }
    }
    const float bdv = valid ? bd[cg] : 0.0f;
    #pragma unroll
    for (int s = 0; s < 4; ++s) {
        bf16x8 vd;
        #pragma unroll
        for (int j = 0; j < 8; ++j) {
            const int k = s * 32 + kg * 8 + j;
            vd[j] = f2bf((valid && k < 100) ? Wd[k * 100 + cg] : 0.0f);
        }
        bWd[s] = vd;
    }

    // per-lane c-state: rows r = kg*4+j (real for kg<2), col cg
    float myC[4] = {0.f, 0.f, 0.f, 0.f};
    long  ob[4];
    #pragma unroll
    for (int j = 0; j < 4; ++j)
        ob[j] = (long)(b0 + kg * 4 + j) * 25000 + cg;   // + t*100 at store time

    // x prefetch: wave w stages batch row w; lane covers 2 k's (float2, 512B/wave)
    const long xbase = ((long)(b0 + wave) * 250) * 128 + lane * 2;
    float2 xp = *(const float2*)&x[xbase];   // t = 0

    const int aoff = m16 * 136 + kg * 8;

    __syncthreads();   // LDS zeros visible before first staging writes

    #pragma unroll 1
    for (int t = 0; t <= 250; ++t) {
        const int buf = t & 1;
        if (t < 250) {
            // stage x_t (rows 0..7; rows 8..15 stay zero from init)
            short2 s2; s2.x = f2bf(xp.x); s2.y = f2bf(xp.y);
            *(short2*)&xA[buf][wave * 136 + lane * 2] = s2;
            const int tn = (t < 249) ? t + 1 : 249;
            xp = *(const float2*)&x[xbase + (long)tn * 128];
        }
        __syncthreads();   // THE barrier: xA(t) + h(t-1) writes visible everywhere

        // h(t-1) fragments — shared by out-GEMM and z-GEMM
        bf16x8 aH[4];
        #pragma unroll
        for (int s = 0; s < 4; ++s)
            aH[s] = *(const bf16x8*)&hA[buf][aoff + s * 32];

        // ---- out_{t-1} = relu(h(t-1) @ Wd + bd) ----
        if (t > 0) {
            f32x4 oacc = {bdv, bdv, bdv, bdv};
            #pragma unroll
            for (int s = 0; s < 4; ++s)
                oacc = __builtin_amdgcn_mfma_f32_16x16x32_bf16(aH[s], bWd[s], oacc, 0, 0, 0);
            if (kg < 2 && valid) {
                #pragma unroll
                for (int j = 0; j < 4; ++j) {
                    const float v = oacc[j] > 0.0f ? oacc[j] : 0.0f;
                    out[ob[j] + (long)(t - 1) * 100] = v;
                }
            }
        }

        // ---- z(t) = bh + x_t@Wi + h(t-1)@Wh ; gates in registers ----
        if (t < 250) {
            f32x4 acc[4];
            #pragma unroll
            for (int G = 0; G < 4; ++G) {
                f32x4 a = {bhv[G], bhv[G], bhv[G], bhv[G]};
                acc[G] = a;
            }
            #pragma unroll
            for (int s = 0; s < 4; ++s) {
                const bf16x8 aX = *(const bf16x8*)&xA[buf][aoff + s * 32];
                #pragma unroll
                for (int G = 0; G < 4; ++G)
                    acc[G] = __builtin_amdgcn_mfma_f32_16x16x32_bf16(aX, bWi[G][s], acc[G], 0, 0, 0);
            }
            #pragma unroll
            for (int s = 0; s < 4; ++s) {
                #pragma unroll
                for (int G = 0; G < 4; ++G)
                    acc[G] = __builtin_amdgcn_mfma_f32_16x16x32_bf16(aH[s], bWh[G][s], acc[G], 0, 0, 0);
            }
            // gates: acc[G][j] = z_G[row kg*4+j][col cg]; real rows are kg<2
            if (kg < 2 && valid) {
                #pragma unroll
                for (int j = 0; j < 4; ++j) {
                    const float ig = fast_sig(acc[0][j]);
                    const float fg = fast_sig(acc[1][j]);
                    const float gg = fast_tanh(acc[2][j]);
                    const float og = fast_sig(acc[3][j]);
                    const float cs = fg * myC[j] + ig * gg;
                    myC[j] = cs;
                    const float h = og * fast_tanh(cs);
                    hA[buf ^ 1][(kg * 4 + j) * 136 + cg] = f2bf(h);
                }
            }
        }
    }
}

extern "C" void kernel_launch(void* const* d_in, const int* in_sizes, int n_in,
                              void* d_out, int out_size, void* d_ws, size_t ws_size,
                              hipStream_t stream) {
    (void)in_sizes; (void)n_in; (void)out_size; (void)d_ws; (void)ws_size;
    const float* x  = (const float*)d_in[0];
    const float* Wi = (const float*)d_in[1];
    const float* Wh = (const float*)d_in[2];
    const float* bh = (const float*)d_in[3];
    const float* Wd = (const float*)d_in[4];
    const float* bd = (const float*)d_in[5];
    float* out = (float*)d_out;

    lstm_fused_all<<<256, TPB, 0, stream>>>(x, Wi, Wh, bh, Wd, bd, out);
}